// Round 11
// baseline (166.674 us; speedup 1.0000x reference)
//
#include <hip/hip_runtime.h>
#include <hip/hip_bf16.h>
#include <hip/hip_fp16.h>

#define B_ 2
#define S_ 1024
#define E_ 128
#define H_ 4
#define D_ 32
#define BHSD (B_ * H_ * S_ * D_)   // 262144 floats per tensor
#define LOG2E 1.44269504088896f

// ---------------------------------------------------------------------------
// Kernel A: fused QKV projection (validated R5/R8 version).
//   Q and K pre-scaled by log2(e) so attention uses bare exp2.
// ---------------------------------------------------------------------------
__global__ __launch_bounds__(128) void qkv_kernel(
    const float* __restrict__ x,
    const float* __restrict__ Wq, const float* __restrict__ bq,
    const float* __restrict__ Wk, const float* __restrict__ bk,
    const float* __restrict__ Wv, const float* __restrict__ bv,
    float* __restrict__ ws) {
  const int mat = blockIdx.y;
  const float* W    = (mat == 0) ? Wq : (mat == 1) ? Wk : Wv;
  const float* bias = (mat == 0) ? bq : (mat == 1) ? bk : bv;
  const float scale = (mat == 2) ? 1.0f : LOG2E;
  float* outbase = ws + (size_t)mat * BHSD;

  const int row0 = blockIdx.x * 8;
  const int t = threadIdx.x;

  __shared__ __align__(16) float xs[8 * E_];
  const float4* xg = (const float4*)(x + (size_t)row0 * E_);
  float4* xs4 = (float4*)xs;
  #pragma unroll
  for (int i = 0; i < 2; ++i) xs4[t + i * 128] = xg[t + i * 128];
  __syncthreads();

  const int col = t;
  const float4* W4 = (const float4*)(W + (size_t)col * E_);

  float acc[8];
  #pragma unroll
  for (int r = 0; r < 8; ++r) acc[r] = 0.f;

  #pragma unroll 4
  for (int c4 = 0; c4 < E_ / 4; ++c4) {
    float4 w = W4[c4];
    #pragma unroll
    for (int r = 0; r < 8; ++r) {
      float4 xv = xs4[r * (E_ / 4) + c4];
      acc[r] += xv.x * w.x + xv.y * w.y + xv.z * w.z + xv.w * w.w;
    }
  }

  const float bcol = bias[col];
  const int h = col >> 5, d = col & 31;
  #pragma unroll
  for (int r = 0; r < 8; ++r) {
    int row = row0 + r;
    int b = row >> 10, s = row & 1023;
    outbase[(((size_t)(b * H_ + h)) * S_ + s) * D_ + d] = (acc[r] + bcol) * scale;
  }
}

// ---------------------------------------------------------------------------
// Kernel B: ultrametric attention, fat-tile / LDS-instruction-minimized.
//   Block = 128 Q-rows x 128 keys (kc chunk of 8), 128 threads = 2 waves.
//   Wave w owns rows [w*64,+64) for EVERYTHING (P is wave-private: no P
//   barriers). Per 64-key tile (2 per block):
//     DIST: lane (rg=lane>>3, kg=lane&7) owns dist[8 rows rg+8i][8 keys
//           kg+8j] over 8 d-chunks: 16 ds_read_b128/chunk for 64x64 pairs.
//     p = exp2(-dist) -> packed fp16, written to Ps[key][slot] where
//           slot = rg*8+i (contiguous 16B per key per lane: 1 b128 write).
//     PV:   lane (rg,kg) owns O[8 rows rg+8i][4 d kg*4..]; per key ONE fp16
//           P read (8 rows, 16B) + ONE V read; 64 keys.
//   l per-lane partial (8 rows x own 8 keys), kg-shfl-reduced at end.
//   DS instrs/wave/tile: 128 DIST + 8 Pw + 128 PV + 8 stage = 272
//   (vs ~536 equivalent in R8) — attacks the measured LDS-throughput bound.
// grid = 8 heads * 8 rowblocks(128) * 8 kc(128 keys) = 512 blocks.
// LDS 55.3 KB -> 2 blocks/CU, 4 waves/CU (1/SIMD; ILP-carried, ~190 VGPR).
// ---------------------------------------------------------------------------
#define STR 36     // f32 LDS row stride (144 B, bank-spread, 16B-aligned)
#define PSTR 72    // fp16 LDS row stride in halfs (144 B, 16B-aligned)

__global__ __launch_bounds__(128, 1) void attn_kernel(
    const float* __restrict__ qg, const float* __restrict__ kg_,
    const float* __restrict__ vg,
    float* __restrict__ part_o, float* __restrict__ part_l) {
  __shared__ __align__(16) float Qs[128 * STR];        // 18432 B
  __shared__ __align__(16) float Ks[64 * STR];         //  9216 B
  __shared__ __align__(16) float Vs[64 * STR];         //  9216 B
  __shared__ __align__(16) __half Ps[2 * 64 * PSTR];   // 18432 B

  const int bx = blockIdx.x;
  const int kc   = bx & 7;             // key chunk 0..7 (128 keys)
  const int rb   = (bx >> 3) & 7;      // row block 0..7 (128 rows)
  const int head = bx >> 6;            // b*H + h, 0..7
  const int t = threadIdx.x;           // 0..127
  const int w = t >> 6;                // wave 0..1
  const int lane = t & 63;
  const int rg = lane >> 3;            // row group: rows {w*64 + rg + 8i}
  const int kg = lane & 7;             // key group (DIST) / dim group (PV)

  const float* qbase = qg  + (size_t)head * S_ * D_ + (size_t)rb * 128 * D_;
  const float* kbase = kg_ + (size_t)head * S_ * D_ + (size_t)kc * 128 * D_;
  const float* vbase = vg  + (size_t)head * S_ * D_ + (size_t)kc * 128 * D_;

  // ---- stage Q (128x32: 8 float4/thread) + K/V tile 0 (4 each) ----
  {
    const float4* qsrc = (const float4*)qbase;
    #pragma unroll
    for (int i = 0; i < 8; ++i) {
      int f = t + i * 128; int r = f >> 3, c = f & 7;
      *(float4*)(Qs + r * STR + c * 4) = qsrc[f];
    }
    const float4* ksrc = (const float4*)kbase;
    const float4* vsrc = (const float4*)vbase;
    #pragma unroll
    for (int i = 0; i < 4; ++i) {
      int f = t + i * 128; int r = f >> 3, c = f & 7;
      *(float4*)(Ks + r * STR + c * 4) = ksrc[f];
      *(float4*)(Vs + r * STR + c * 4) = vsrc[f];
    }
  }

  float O[8][4];
  #pragma unroll
  for (int i = 0; i < 8; ++i)
    #pragma unroll
    for (int c = 0; c < 4; ++c) O[i][c] = 0.f;
  float lrow[8];
  #pragma unroll
  for (int i = 0; i < 8; ++i) lrow[i] = 0.f;

  __half* Psw = Ps + (size_t)w * 64 * PSTR;   // wave-private P buffer
  const float* Qw = Qs + (size_t)(w * 64) * STR;

  __syncthreads();

  #pragma unroll
  for (int it = 0; it < 2; ++it) {
    // ---- DIST: dist[8 rows][8 keys] over 8 d-chunks ----
    float dist[8][8];
    #pragma unroll
    for (int i = 0; i < 8; ++i)
      #pragma unroll
      for (int j = 0; j < 8; ++j) dist[i][j] = 0.f;

    #pragma unroll
    for (int c = 0; c < 8; ++c) {
      float4 qv[8];
      #pragma unroll
      for (int i = 0; i < 8; ++i)
        qv[i] = *(const float4*)(Qw + (rg + 8 * i) * STR + c * 4);
      #pragma unroll
      for (int j = 0; j < 8; ++j) {
        float4 kv = *(const float4*)(Ks + (kg + 8 * j) * STR + c * 4);
        #pragma unroll
        for (int i = 0; i < 8; ++i) {
          float m0 = fmaxf(fabsf(qv[i].x - kv.x), fabsf(qv[i].y - kv.y));
          float m1 = fmaxf(fabsf(qv[i].z - kv.z), fabsf(qv[i].w - kv.w));
          dist[i][j] = fmaxf(dist[i][j], fmaxf(m0, m1));
        }
      }
    }

    // ---- p = exp2(-dist); accumulate l; pack fp16; write P (wave-private) --
    #pragma unroll
    for (int j = 0; j < 8; ++j) {
      #pragma unroll
      for (int i = 0; i < 8; ++i) {
        float p = exp2f(-dist[i][j]);    // dist pre-scaled by log2e
        dist[i][j] = p;
        lrow[i] += p;
      }
      __half2 hh[4];
      hh[0] = __floats2half2_rn(dist[0][j], dist[1][j]);
      hh[1] = __floats2half2_rn(dist[2][j], dist[3][j]);
      hh[2] = __floats2half2_rn(dist[4][j], dist[5][j]);
      hh[3] = __floats2half2_rn(dist[6][j], dist[7][j]);
      *(uint4*)(Psw + (kg + 8 * j) * PSTR + rg * 8) = *(uint4*)hh;
    }
    // no barrier: P rows are wave-private; same-wave LDS RAW ordered by lgkmcnt

    // ---- PV: O[8r][4d] += over all 64 keys of this tile ----
    #pragma unroll 8
    for (int tk = 0; tk < 64; ++tk) {
      uint4 pr = *(const uint4*)(Psw + tk * PSTR + rg * 8);
      float4 vv = *(const float4*)(Vs + tk * STR + kg * 4);
      __half2* ph = (__half2*)&pr;
      float2 f0 = __half22float2(ph[0]);
      float2 f1 = __half22float2(ph[1]);
      float2 f2 = __half22float2(ph[2]);
      float2 f3 = __half22float2(ph[3]);
      O[0][0] = fmaf(f0.x, vv.x, O[0][0]); O[0][1] = fmaf(f0.x, vv.y, O[0][1]);
      O[0][2] = fmaf(f0.x, vv.z, O[0][2]); O[0][3] = fmaf(f0.x, vv.w, O[0][3]);
      O[1][0] = fmaf(f0.y, vv.x, O[1][0]); O[1][1] = fmaf(f0.y, vv.y, O[1][1]);
      O[1][2] = fmaf(f0.y, vv.z, O[1][2]); O[1][3] = fmaf(f0.y, vv.w, O[1][3]);
      O[2][0] = fmaf(f1.x, vv.x, O[2][0]); O[2][1] = fmaf(f1.x, vv.y, O[2][1]);
      O[2][2] = fmaf(f1.x, vv.z, O[2][2]); O[2][3] = fmaf(f1.x, vv.w, O[2][3]);
      O[3][0] = fmaf(f1.y, vv.x, O[3][0]); O[3][1] = fmaf(f1.y, vv.y, O[3][1]);
      O[3][2] = fmaf(f1.y, vv.z, O[3][2]); O[3][3] = fmaf(f1.y, vv.w, O[3][3]);
      O[4][0] = fmaf(f2.x, vv.x, O[4][0]); O[4][1] = fmaf(f2.x, vv.y, O[4][1]);
      O[4][2] = fmaf(f2.x, vv.z, O[4][2]); O[4][3] = fmaf(f2.x, vv.w, O[4][3]);
      O[5][0] = fmaf(f2.y, vv.x, O[5][0]); O[5][1] = fmaf(f2.y, vv.y, O[5][1]);
      O[5][2] = fmaf(f2.y, vv.z, O[5][2]); O[5][3] = fmaf(f2.y, vv.w, O[5][3]);
      O[6][0] = fmaf(f3.x, vv.x, O[6][0]); O[6][1] = fmaf(f3.x, vv.y, O[6][1]);
      O[6][2] = fmaf(f3.x, vv.z, O[6][2]); O[6][3] = fmaf(f3.x, vv.w, O[6][3]);
      O[7][0] = fmaf(f3.y, vv.x, O[7][0]); O[7][1] = fmaf(f3.y, vv.y, O[7][1]);
      O[7][2] = fmaf(f3.y, vv.z, O[7][2]); O[7][3] = fmaf(f3.y, vv.w, O[7][3]);
    }

    __syncthreads();   // both waves done reading Ks/Vs
    if (it == 0) {
      const float4* ksrc = (const float4*)(kbase + 64 * D_);
      const float4* vsrc = (const float4*)(vbase + 64 * D_);
      #pragma unroll
      for (int i = 0; i < 4; ++i) {
        int f = t + i * 128; int r = f >> 3, c = f & 7;
        *(float4*)(Ks + r * STR + c * 4) = ksrc[f];
        *(float4*)(Vs + r * STR + c * 4) = vsrc[f];
      }
      __syncthreads();
    }
  }

  // ---- reduce l across kg lanes (butterfly over lane bits 0..2) ----
  #pragma unroll
  for (int i = 0; i < 8; ++i) {
    lrow[i] += __shfl_xor(lrow[i], 1);
    lrow[i] += __shfl_xor(lrow[i], 2);
    lrow[i] += __shfl_xor(lrow[i], 4);
  }

  // ---- write raw partials (no cross-wave merge: wave owns its 64 rows) ----
  const int rt = head * 8 + rb;                       // 0..63
  const size_t base = ((size_t)(rt * 8 + kc)) * 128 + w * 64;
  #pragma unroll
  for (int i = 0; i < 8; ++i) {
    const int ar = rg + 8 * i;
    *(float4*)(part_o + (base + ar) * 32 + kg * 4) =
        make_float4(O[i][0], O[i][1], O[i][2], O[i][3]);
  }
  if (kg == 0) {
    #pragma unroll
    for (int i = 0; i < 8; ++i)
      part_l[base + rg + 8 * i] = lrow[i];
  }
}

// ---------------------------------------------------------------------------
// Kernel C: merge 8 kc-partials -> att rows in LDS -> out = att @ Wo^T + bo
// part layout: [rt = head*8+rb][8 kc][128 row][32 d]
// ---------------------------------------------------------------------------
__global__ __launch_bounds__(128) void out_kernel(
    const float* __restrict__ part_o, const float* __restrict__ part_l,
    const float* __restrict__ Wo, const float* __restrict__ bo,
    float* __restrict__ out) {
  const int row0 = blockIdx.x * 8;
  const int t = threadIdx.x;

  __shared__ __align__(16) float xs[8 * E_];

  const int e = t;
  const int h = e >> 5, d = e & 31;
  #pragma unroll
  for (int i = 0; i < 8; ++i) {
    const int r = row0 + i;
    const int b = r >> 10, s = r & 1023;
    const int rt = (b * H_ + h) * 8 + (s >> 7);
    const int lrow = s & 127;
    float acc = 0.f, lsum = 0.f;
    #pragma unroll
    for (int kc = 0; kc < 8; ++kc) {
      const size_t base = ((size_t)(rt * 8 + kc)) * 128 + lrow;
      acc  += part_o[base * 32 + d];
      lsum += part_l[base];
    }
    xs[i * E_ + e] = acc / lsum;
  }
  __syncthreads();

  const int col = t;
  const float4* W4 = (const float4*)(Wo + (size_t)col * E_);
  const float4* xs4 = (const float4*)xs;

  float acc[8];
  #pragma unroll
  for (int r = 0; r < 8; ++r) acc[r] = 0.f;

  #pragma unroll 4
  for (int c4 = 0; c4 < E_ / 4; ++c4) {
    float4 w = W4[c4];
    #pragma unroll
    for (int r = 0; r < 8; ++r) {
      float4 xv = xs4[r * (E_ / 4) + c4];
      acc[r] += xv.x * w.x + xv.y * w.y + xv.z * w.z + xv.w * w.w;
    }
  }

  const float bcol = bo[col];
  #pragma unroll
  for (int r = 0; r < 8; ++r)
    out[(size_t)(row0 + r) * E_ + col] = acc[r] + bcol;
}

// ---------------------------------------------------------------------------
extern "C" void kernel_launch(void* const* d_in, const int* in_sizes, int n_in,
                              void* d_out, int out_size, void* d_ws, size_t ws_size,
                              hipStream_t stream) {
  const float* x  = (const float*)d_in[0];
  const float* Wq = (const float*)d_in[1];
  const float* bq = (const float*)d_in[2];
  const float* Wk = (const float*)d_in[3];
  const float* bk = (const float*)d_in[4];
  const float* Wv = (const float*)d_in[5];
  const float* bv = (const float*)d_in[6];
  const float* Wo = (const float*)d_in[7];
  const float* bo = (const float*)d_in[8];
  float* ws  = (float*)d_ws;
  float* out = (float*)d_out;

  // ws layout (floats):
  //   [0, BHSD)          q (log2e-scaled)
  //   [BHSD, 2*BHSD)     k (log2e-scaled)
  //   [2*BHSD, 3*BHSD)   v
  //   [3*BHSD, +2097152) part_o : [64 rt][8 kc][128 row][32 d]
  //   then 65536         part_l : [64 rt][8 kc][128 row]
  float* qd = ws;
  float* kd = ws + (size_t)BHSD;
  float* vd = ws + 2 * (size_t)BHSD;
  float* part_o = ws + 3 * (size_t)BHSD;
  float* part_l = part_o + (size_t)64 * 8 * 128 * 32;

  qkv_kernel<<<dim3((B_ * S_) / 8, 3), 128, 0, stream>>>(x, Wq, bq, Wk, bk, Wv, bv, ws);
  attn_kernel<<<dim3(512), 128, 0, stream>>>(qd, kd, vd, part_o, part_l);
  out_kernel<<<dim3((B_ * S_) / 8), 128, 0, stream>>>(part_o, part_l, Wo, bo, out);
}